// Round 2
// baseline (8446.420 us; speedup 1.0000x reference)
//
#include <hip/hip_runtime.h>
#include <hip/hip_bf16.h>
#include <stdint.h>

#define B_ 64
#define T_ 2048
#define H_ 256
#define CHUNK 16
#define NCH (T_ / CHUNK)

typedef unsigned int u32;
typedef unsigned short u16;

static __device__ __forceinline__ float bf2f(u16 v) {
  return __builtin_bit_cast(float, (u32)v << 16);
}
static __device__ __forceinline__ u16 f2bf(float f) {
  u32 u = __builtin_bit_cast(u32, f);
  u32 r = (u + 0x7fffu + ((u >> 16) & 1u)) >> 16;  // RNE; finite inputs only
  return (u16)r;
}

// ---- dtype detector: W_ih0 ~ U(-1/16,1/16). As bf16, exponent field < 127
// always. As f32 reinterpreted to u16 pairs, even words are random mantissa
// bits -> ~50% have exponent >= 127. Flag: 1 = inputs are f32.
__global__ __launch_bounds__(256) void detect_k(const u16* w0, u32* flag) {
  __shared__ int cnt[256];
  const int j = threadIdx.x;
  int c = 0;
#pragma unroll
  for (int k = 0; k < 8; ++k) {
    u16 v = w0[j * 8 + k];
    c += (((v >> 7) & 0xFF) >= 127) ? 1 : 0;
  }
  cnt[j] = c;
  __syncthreads();
  if (j == 0) {
    int t = 0;
    for (int i = 0; i < 256; ++i) t += cnt[i];
    *flag = (t > 64) ? 1u : 0u;
  }
}

// Load W row j (256 elems) as 128 packed bf16 pairs (lo = elem 2k, hi = 2k+1).
template <bool F32>
static __device__ __forceinline__ void load_wrow(const void* W, int j, u32* w) {
  if constexpr (F32) {
    const float4* r = (const float4*)((const float*)W + (size_t)j * H_);
#pragma unroll
    for (int q = 0; q < 64; ++q) {
      float4 v = r[q];
      w[2 * q + 0] = (u32)f2bf(v.x) | ((u32)f2bf(v.y) << 16);
      w[2 * q + 1] = (u32)f2bf(v.z) | ((u32)f2bf(v.w) << 16);
    }
  } else {
    const uint4* r = (const uint4*)((const u16*)W + (size_t)j * H_);
#pragma unroll
    for (int q = 0; q < 32; ++q) {
      uint4 v = r[q];
      w[4 * q + 0] = v.x; w[4 * q + 1] = v.y; w[4 * q + 2] = v.z; w[4 * q + 3] = v.w;
    }
  }
}

// dot(w_row_bf16_packed, h_f32[256]); h read from LDS at uniform addresses.
static __device__ __forceinline__ float dot256(const u32* w, const float* h) {
  float a0 = 0.f, a1 = 0.f, a2 = 0.f, a3 = 0.f;
#pragma unroll
  for (int q = 0; q < 64; ++q) {
    u32 wa = w[2 * q], wb = w[2 * q + 1];
    float4 hv = ((const float4*)h)[q];  // uniform address -> broadcast
    a0 = fmaf(bf2f((u16)wa), hv.x, a0);
    a1 = fmaf(bf2f((u16)(wa >> 16)), hv.y, a1);
    a2 = fmaf(bf2f((u16)wb), hv.z, a2);
    a3 = fmaf(bf2f((u16)(wb >> 16)), hv.w, a3);
  }
  return (a0 + a1) + (a2 + a3);
}

// pre[r, j] = dot(X[r,:], Wih[j,:]) + bih[j] + bhh[j]
// Safe in-place (X == pre): row r+1 is loaded before row r is stored; rows
// are disjoint across workgroups.
template <bool F32>
static __device__ void pre_body(char* smem, const void* X, const void* Wih,
                                const void* bih, const void* bhh, void* pre,
                                int rows_per_wg) {
  float(*xl)[H_] = (float(*)[H_])smem;  // [2][256] f32
  const int j = threadIdx.x;
  u32 w[128];
  load_wrow<F32>(Wih, j, w);
  const float bias = F32 ? (((const float*)bih)[j] + ((const float*)bhh)[j])
                         : (bf2f(((const u16*)bih)[j]) + bf2f(((const u16*)bhh)[j]));
  const size_t r0 = (size_t)blockIdx.x * rows_per_wg;

  if (F32) xl[0][j] = ((const float*)X)[r0 * H_ + j];
  else     xl[0][j] = bf2f(((const u16*)X)[r0 * H_ + j]);
  __syncthreads();

  for (int i = 0; i < rows_per_wg; ++i) {
    const int buf = i & 1;
    const size_t r = r0 + i;
    if (i + 1 < rows_per_wg) {
      if (F32) xl[buf ^ 1][j] = ((const float*)X)[(r + 1) * H_ + j];
      else     xl[buf ^ 1][j] = bf2f(((const u16*)X)[(r + 1) * H_ + j]);
    }
    const float acc = dot256(w, xl[buf]) + bias;
    if (F32) ((float*)pre)[r * H_ + j] = acc;
    else     ((u16*)pre)[r * H_ + j] = f2bf(acc);
    __syncthreads();
  }
}

// h_t = tanh(pre[t] + Whh . h_{t-1}); one WG per batch element; thread j owns
// output j; Whh row j in VGPRs; h double-buffered f32 in LDS; pre staged in
// 16-step chunks (issue loads at s==0, LDS-write at s==CHUNK-1).
// Safe in-place (pre == out): chunk c+1 is fully loaded to registers before
// any of its rows are overwritten (writes trail by a full chunk).
template <bool F32>
static __device__ void rec_body(char* smem, const void* pre, const void* Whh,
                                void* out) {
  float* hbuf = (float*)smem;                       // [2][256] f32
  uint4* pls = (uint4*)(smem + 2 * H_ * sizeof(float));
  const int NU = F32 ? 1024 : 512;                  // uint4 per chunk
  const int KS = F32 ? 4 : 2;                       // uint4 per thread per stage
  const int j = threadIdx.x;
  u32 w[128];
  load_wrow<F32>(Whh, j, w);
  const size_t base = (size_t)blockIdx.x * (size_t)(T_ * H_);
  const size_t eb = F32 ? 4 : 2;  // element bytes

  hbuf[j] = 0.f;
  hbuf[H_ + j] = 0.f;
  {
    const uint4* s0 = (const uint4*)((const char*)pre + base * eb);
#pragma unroll 4
    for (int k = 0; k < KS; ++k) pls[k * 256 + j] = s0[k * 256 + j];
  }
  __syncthreads();

  uint4 st[4];
  int hb = 0;
  for (int c = 0; c < NCH; ++c) {
    const int pb = c & 1;
    const char* pchunk = (const char*)(pls + (size_t)pb * NU);
    for (int s = 0; s < CHUNK; ++s) {
      float pc;
      if (F32) pc = ((const float*)pchunk)[s * H_ + j];
      else     pc = bf2f(((const u16*)pchunk)[s * H_ + j]);
      if (s == 0 && c + 1 < NCH) {  // issue next-chunk loads early
        const uint4* src = (const uint4*)((const char*)pre +
                            (base + (size_t)(c + 1) * CHUNK * H_) * eb);
#pragma unroll 4
        for (int k = 0; k < KS; ++k) st[k] = src[k * 256 + j];
      }
      const float acc = dot256(w, hbuf + (size_t)hb * H_);
      const float hv = tanhf(acc + pc);
      if (s == CHUNK - 1 && c + 1 < NCH) {  // write-late into the other buffer
        uint4* dst = pls + (size_t)(pb ^ 1) * NU;
#pragma unroll 4
        for (int k = 0; k < KS; ++k) dst[k * 256 + j] = st[k];
      }
      hbuf[(size_t)(hb ^ 1) * H_ + j] = hv;
      const size_t t = (size_t)(c * CHUNK + s);
      if (F32) ((float*)out)[base + t * H_ + j] = hv;
      else     ((u16*)out)[base + t * H_ + j] = f2bf(hv);
      __syncthreads();
      hb ^= 1;
    }
  }
}

__global__ __launch_bounds__(256) void rnn_pre_k(const void* X, const void* W,
                                                 const void* bi, const void* bh,
                                                 void* pre, int rpw,
                                                 const u32* flag) {
  __shared__ __align__(16) char smem[2 * H_ * sizeof(float)];
  if (*flag) pre_body<true>(smem, X, W, bi, bh, pre, rpw);
  else       pre_body<false>(smem, X, W, bi, bh, pre, rpw);
}

__global__ __launch_bounds__(256) void rnn_rec_k(const void* pre, const void* W,
                                                 void* out, const u32* flag) {
  __shared__ __align__(16) char smem[2 * H_ * sizeof(float) + 2 * CHUNK * H_ * sizeof(float)];
  if (*flag) rec_body<true>(smem, pre, W, out);
  else       rec_body<false>(smem, pre, W, out);
}

extern "C" void kernel_launch(void* const* d_in, const int* in_sizes, int n_in,
                              void* d_out, int out_size, void* d_ws, size_t ws_size,
                              hipStream_t stream) {
  (void)in_sizes; (void)n_in; (void)out_size; (void)ws_size;
  const void* x    = d_in[0];
  const void* Wih0 = d_in[1];
  const void* Whh0 = d_in[2];
  const void* bih0 = d_in[3];
  const void* bhh0 = d_in[4];
  const void* Wih1 = d_in[5];
  const void* Whh1 = d_in[6];
  const void* bih1 = d_in[7];
  const void* bhh1 = d_in[8];
  u32* flag = (u32*)d_ws;

  detect_k<<<dim3(1), dim3(256), 0, stream>>>((const u16*)Wih0, flag);

  const int R = B_ * T_;
  const int RPW = 64;
  rnn_pre_k<<<dim3(R / RPW), dim3(256), 0, stream>>>(x, Wih0, bih0, bhh0, d_out, RPW, flag);
  rnn_rec_k<<<dim3(B_), dim3(256), 0, stream>>>(d_out, Whh0, d_out, flag);
  rnn_pre_k<<<dim3(R / RPW), dim3(256), 0, stream>>>(d_out, Wih1, bih1, bhh1, d_out, RPW, flag);
  rnn_rec_k<<<dim3(B_), dim3(256), 0, stream>>>(d_out, Whh1, d_out, flag);
}

// Round 4
// 4246.640 us; speedup vs baseline: 1.9890x; 1.9890x over previous
//
#include <hip/hip_runtime.h>
#include <hip/hip_bf16.h>
#include <stdint.h>

#define B_ 64
#define T_ 2048
#define H_ 256

typedef unsigned int u32;
typedef unsigned short u16;
typedef __attribute__((ext_vector_type(8))) short short8;
typedef __attribute__((ext_vector_type(4))) float f32x4;

// LDS tile: 16 rows x 256 bf16 cols, row stride 512 B, XOR-swizzled so that
// 64-lane ds_read_b128 at (row=lane&15, k-slice=(lane>>4)*8) spreads 8-way
// (the b128 optimum) instead of 4 slots. Same formula on write and read.
#define SWZ(row, byte) (((row) * 512) + ((byte) ^ (((row) & 7) << 4)))

static __device__ __forceinline__ u16 f2bf(float f) {
  u32 u = __builtin_bit_cast(u32, f);
  u32 r = (u + 0x7fffu + ((u >> 16) & 1u)) >> 16;  // RNE; finite inputs only
  return (u16)r;
}
static __device__ __forceinline__ u32 f2u(float a, float b) {
  return (u32)f2bf(a) | ((u32)f2bf(b) << 16);
}
static __device__ __forceinline__ uint4 pack8(float4 a, float4 b) {
  uint4 r;
  r.x = f2u(a.x, a.y); r.y = f2u(a.z, a.w);
  r.z = f2u(b.x, b.y); r.w = f2u(b.z, b.w);
  return r;
}
static __device__ __forceinline__ short8 as8(uint4 v) {
  return __builtin_bit_cast(short8, v);
}
static __device__ __forceinline__ float fast_tanh(float x) {
  float e = __expf(2.0f * x);        // exp->0 or inf saturates tanh correctly
  return 1.0f - 2.0f / (e + 1.0f);
}

// wf[q][kc] = W[(wv*4+q)*16 + (lane&15)][kc*32 + (lane>>4)*8 .. +8] as bf16x8.
// This is the verified A-operand layout for mfma_f32_16x16x32_bf16:
// lane&15 -> M-row, (lane>>4)*8+e -> k (contiguous 8), D: col=lane&15(N),
// row=(lane>>4)*4+reg (M).  [learn_hip m89/m91/m92]
static __device__ __forceinline__ void load_wfrag(const float* W, int wv, int bl,
                                                  int g, uint4 wf[4][8]) {
#pragma unroll
  for (int q = 0; q < 4; ++q) {
    const float* wr = W + (size_t)((wv * 4 + q) * 16 + bl) * H_ + g * 8;
#pragma unroll
    for (int kc = 0; kc < 8; ++kc) {
      float4 a = *(const float4*)(wr + kc * 32);
      float4 b = *(const float4*)(wr + kc * 32 + 4);
      wf[q][kc] = pack8(a, b);
    }
  }
}

// pre[row, j] = dot(X[row,:], W[j,:]) + bi[j] + bh[j]   (all f32 global)
// Per WG: W fragments in VGPRs, X 16-row tiles staged f32->bf16 into
// swizzled LDS (double-buffered), MFMA, f32 epilogue. In-place safe
// (X == pre for layer 1): tile rows are read (or prefetched) strictly
// before those rows are stored, and WGs own disjoint rows.
__global__ __launch_bounds__(256, 2) void pre_mfma(const float* X, const float* W,
                                                   const float* bi, const float* bh,
                                                   float* P, int tpw) {
  __shared__ char sb_[2][8192];
  const int tid = threadIdx.x;
  const int lane = tid & 63, wv = tid >> 6;
  const int bl = lane & 15, g = lane >> 4;

  uint4 wf[4][8];
  load_wfrag(W, wv, bl, g, wf);
  float4 bias[4];
#pragma unroll
  for (int q = 0; q < 4; ++q) {
    const int j0 = (wv * 4 + q) * 16 + g * 4;
    float4 a = *(const float4*)(bi + j0);
    float4 c = *(const float4*)(bh + j0);
    bias[q].x = a.x + c.x; bias[q].y = a.y + c.y;
    bias[q].z = a.z + c.z; bias[q].w = a.w + c.w;
  }

  const size_t row0 = (size_t)blockIdx.x * tpw * 16;
  const int sr = tid >> 4, sc = (tid & 15) * 16;  // staging: row, col (16 f32)
  float4 s0, s1, s2, s3;
  {
    const float4* xs = (const float4*)(X + (row0 + sr) * H_ + sc);
    s0 = xs[0]; s1 = xs[1]; s2 = xs[2]; s3 = xs[3];
  }

  for (int i = 0; i < tpw; ++i) {
    char* sb = sb_[i & 1];
    *(uint4*)(sb + SWZ(sr, sc * 2)) = pack8(s0, s1);
    *(uint4*)(sb + SWZ(sr, sc * 2 + 16)) = pack8(s2, s3);
    __syncthreads();
    if (i + 1 < tpw) {  // prefetch next tile; consumed at next ds_write
      const float4* xn = (const float4*)(X + (row0 + (i + 1) * 16 + sr) * H_ + sc);
      s0 = xn[0]; s1 = xn[1]; s2 = xn[2]; s3 = xn[3];
    }
    uint4 hf[8];
#pragma unroll
    for (int kc = 0; kc < 8; ++kc)
      hf[kc] = *(const uint4*)(sb + SWZ(bl, kc * 64 + g * 16));
    f32x4 acc[4];
#pragma unroll
    for (int q = 0; q < 4; ++q) {
      acc[q] = (f32x4){0.f, 0.f, 0.f, 0.f};
#pragma unroll
      for (int kc = 0; kc < 8; ++kc)
        acc[q] = __builtin_amdgcn_mfma_f32_16x16x32_bf16(as8(wf[q][kc]), as8(hf[kc]),
                                                         acc[q], 0, 0, 0);
    }
#pragma unroll
    for (int q = 0; q < 4; ++q) {
      const int j0 = (wv * 4 + q) * 16 + g * 4;
      float4 o;
      o.x = acc[q][0] + bias[q].x; o.y = acc[q][1] + bias[q].y;
      o.z = acc[q][2] + bias[q].z; o.w = acc[q][3] + bias[q].w;
      *(float4*)(P + (row0 + i * 16 + bl) * H_ + j0) = o;
    }
    __syncthreads();  // all reads of sb_[i&1] done before iter i+2 rewrites it
  }
}

// h_t = tanh(pre[t] + Whh . h_{t-1}); 16 batch elements per WG (4 WGs).
// Whh fragments in VGPRs; h[16][256] bf16 double-buffered in swizzled LDS
// (8 KB each): per wave per step just 8 ds_read_b128 + 4 ds_write_b64.
// pre prefetched depth-2 into named register rings (no runtime indexing).
// Raw s_barrier + lgkmcnt(0): prefetch vmcnt survives across barriers.
// In-place safe (pre == out): pre[t] was consumed (loaded at t-2) before
// out[t] is stored at t.
__global__ __launch_bounds__(256, 1) void rec_mfma(const float* pre, const float* W,
                                                   float* out) {
  __shared__ char hb_[2][8192];
  const int tid = threadIdx.x;
  const int lane = tid & 63, wv = tid >> 6;
  const int bl = lane & 15, g = lane >> 4;
  const int b0 = blockIdx.x * 16;

  uint4 wf[4][8];
  load_wfrag(W, wv, bl, g, wf);

  {  // h(-1) = 0
    uint4 z = make_uint4(0, 0, 0, 0);
    ((uint4*)hb_[0])[tid] = z; ((uint4*)hb_[0])[tid + 256] = z;
    ((uint4*)hb_[1])[tid] = z; ((uint4*)hb_[1])[tid + 256] = z;
  }

  const float* prow = pre + (size_t)(b0 + bl) * T_ * H_;
  float* orow = out + (size_t)(b0 + bl) * T_ * H_;
  float4 pr0[4], pr1[4];
#pragma unroll
  for (int q = 0; q < 4; ++q) {
    const int j0 = (wv * 4 + q) * 16 + g * 4;
    pr0[q] = *(const float4*)(prow + 0 * H_ + j0);
    pr1[q] = *(const float4*)(prow + 1 * H_ + j0);
  }
  __syncthreads();

  auto step = [&](int t, float4 (&pr)[4], char* rbuf, char* wbuf) {
    uint4 hf[8];
#pragma unroll
    for (int kc = 0; kc < 8; ++kc)
      hf[kc] = *(const uint4*)(rbuf + SWZ(bl, kc * 64 + g * 16));
    f32x4 acc[4];
#pragma unroll
    for (int q = 0; q < 4; ++q) {
      acc[q] = (f32x4){0.f, 0.f, 0.f, 0.f};
#pragma unroll
      for (int kc = 0; kc < 8; ++kc)
        acc[q] = __builtin_amdgcn_mfma_f32_16x16x32_bf16(as8(wf[q][kc]), as8(hf[kc]),
                                                         acc[q], 0, 0, 0);
    }
#pragma unroll
    for (int q = 0; q < 4; ++q) {
      const int j0 = (wv * 4 + q) * 16 + g * 4;
      float4 p = pr[q];
      float v0 = fast_tanh(acc[q][0] + p.x);
      float v1 = fast_tanh(acc[q][1] + p.y);
      float v2 = fast_tanh(acc[q][2] + p.z);
      float v3 = fast_tanh(acc[q][3] + p.w);
      float4 o; o.x = v0; o.y = v1; o.z = v2; o.w = v3;
      *(float4*)(orow + (size_t)t * H_ + j0) = o;
      uint2 hw; hw.x = f2u(v0, v1); hw.y = f2u(v2, v3);
      *(uint2*)(wbuf + SWZ(bl, j0 * 2)) = hw;            // h for step t+1
      if (t + 2 < T_)                                     // prefetch pre[t+2]
        pr[q] = *(const float4*)(prow + (size_t)(t + 2) * H_ + j0);
    }
    // one barrier per step; LDS-only drain so prefetch loads stay in flight
    asm volatile("s_waitcnt lgkmcnt(0)" ::: "memory");
    __builtin_amdgcn_s_barrier();
    __builtin_amdgcn_sched_barrier(0);
  };

  for (int t = 0; t < T_; t += 2) {  // manual 2-unroll keeps pr rings in regs
    step(t, pr0, hb_[0], hb_[1]);
    step(t + 1, pr1, hb_[1], hb_[0]);
  }
}

extern "C" void kernel_launch(void* const* d_in, const int* in_sizes, int n_in,
                              void* d_out, int out_size, void* d_ws, size_t ws_size,
                              hipStream_t stream) {
  (void)in_sizes; (void)n_in; (void)out_size; (void)d_ws; (void)ws_size;
  const float* x    = (const float*)d_in[0];
  const float* Wih0 = (const float*)d_in[1];
  const float* Whh0 = (const float*)d_in[2];
  const float* bih0 = (const float*)d_in[3];
  const float* bhh0 = (const float*)d_in[4];
  const float* Wih1 = (const float*)d_in[5];
  const float* Whh1 = (const float*)d_in[6];
  const float* bih1 = (const float*)d_in[7];
  const float* bhh1 = (const float*)d_in[8];
  float* out = (float*)d_out;

  const int TPW = 8;                       // 16-row tiles per workgroup
  const int NWG = (B_ * T_) / (TPW * 16);  // 1024
  pre_mfma<<<dim3(NWG), dim3(256), 0, stream>>>(x, Wih0, bih0, bhh0, out, TPW);
  rec_mfma<<<dim3(B_ / 16), dim3(256), 0, stream>>>(out, Whh0, out);
  pre_mfma<<<dim3(NWG), dim3(256), 0, stream>>>(out, Wih1, bih1, bhh1, out, TPW);
  rec_mfma<<<dim3(B_ / 16), dim3(256), 0, stream>>>(out, Whh1, out);
}